// Round 2
// 185.520 us; speedup vs baseline: 1.0461x; 1.0461x over previous
//
#include <hip/hip_runtime.h>
#include <cstddef>

#define BSZ   2
#define NN    384
#define DATOM 512
#define DPAIR 128
#define DHID  32

// ---------------------------------------------------------------------------
// Workspace layout (float offsets):
//   abuf [BSZ*NN][32]  fp32       offset 0         (24576 floats)
//   bbh  [BSZ][NN][32] bf16 hi    offset 24576     (12288 floats)
//   bbl  [BSZ][NN][32] bf16 lo    offset 36864     (12288 floats)
//   Th   [BSZ*NN][128][32] bf16   offset 49152     (1572864 floats)
//   Tl   [BSZ*NN][128][32] bf16   offset 1622016   (1572864 floats)
// Total 3,194,880 floats — identical footprint to previous version.
// ---------------------------------------------------------------------------

#define COMP4(v,i) ((i)==0?(v).x:(i)==1?(v).y:(i)==2?(v).z:(v).w)

typedef __attribute__((ext_vector_type(8))) short bf16x8;
typedef __attribute__((ext_vector_type(4))) float f32x4;

static __device__ __forceinline__ unsigned short f2bf(float x) {
    unsigned int u = __float_as_uint(x);
    u += 0x7fffu + ((u >> 16) & 1u);          // round-to-nearest-even
    return (unsigned short)(u >> 16);
}
static __device__ __forceinline__ float bf2f(unsigned short h) {
    return __uint_as_float(((unsigned int)h) << 16);
}

// Kernel A: ab = (m @ W_in^T + b_in) * op_mask.
// 'a' half -> abuf fp32 (k_T input); 'b' half -> split-bf16 [b][j][y] planes
// (k_main A-operand: lane reads 8 consecutive y = 16B contiguous).
__global__ __launch_bounds__(256) void k_ab(
    const float* __restrict__ m, const float* __restrict__ op_mask,
    const float* __restrict__ W_in, const float* __restrict__ b_in,
    float* __restrict__ abuf,
    unsigned short* __restrict__ bbh, unsigned short* __restrict__ bbl)
{
    const int t   = threadIdx.x;
    const int h   = t >> 2;          // 0..63
    const int q   = t & 3;           // d-offset q*4, stride 16 floats
    const int row = blockIdx.x;      // b*NN + n

    const float* wrow = W_in + (size_t)h * DATOM + q * 4;
    const float* mrow = m + (size_t)row * DATOM + q * 4;
    float acc = 0.f;
#pragma unroll
    for (int k = 0; k < 32; ++k) {
        const float4 w  = *(const float4*)(wrow + k * 16);
        const float4 mm = *(const float4*)(mrow + k * 16);
        acc += w.x * mm.x + w.y * mm.y + w.z * mm.z + w.w * mm.w;
    }
    acc += __shfl_xor(acc, 1);
    acc += __shfl_xor(acc, 2);
    if (q == 0) {
        const float val = (acc + b_in[h]) * op_mask[row];
        if (h < DHID) {
            abuf[(size_t)row * DHID + h] = val;
        } else {
            const unsigned short hi = f2bf(val);
            const float lo = val - bf2f(hi);
            const size_t idx = (size_t)row * DHID + (h - DHID);  // row = b*NN+n
            bbh[idx] = hi;
            bbl[idx] = f2bf(lo);
        }
    }
}

// Kernel B: T[b,i,p,y] = sum_x a[b,i,x] * W_out[p, x*32+y], fp32 compute,
// epilogue splits into bf16 hi/lo planes (k_main B-operand: [p][y] = [n][k],
// lane reads 8 consecutive y = 16B contiguous).
__global__ __launch_bounds__(256) void k_T(
    const float* __restrict__ abuf, const float* __restrict__ W_out,
    unsigned short* __restrict__ Th, unsigned short* __restrict__ Tl)
{
    __shared__ __align__(16) float alds[8 * DHID];
    const int t   = threadIdx.x;
    const int ig  = blockIdx.x >> 3;   // 0..95
    const int oct = blockIdx.x & 7;    // p base = oct*16
    const int r0  = ig * 8;            // flat (b*NN+i) base

    alds[t] = abuf[(size_t)r0 * DHID + t];
    __syncthreads();

    const int y  = t & 31;
    const int pg = t >> 5;             // 0..7

    float acc[2][8];
#pragma unroll
    for (int c = 0; c < 2; ++c)
#pragma unroll
        for (int i = 0; i < 8; ++i) acc[c][i] = 0.f;

#pragma unroll
    for (int xc = 0; xc < 8; ++xc) {
        float4 a4[8];
#pragma unroll
        for (int i = 0; i < 8; ++i)
            a4[i] = *(const float4*)&alds[i * DHID + xc * 4];  // broadcast
#pragma unroll
        for (int xi = 0; xi < 4; ++xi) {
            const int x = xc * 4 + xi;
            float w[2];
#pragma unroll
            for (int c = 0; c < 2; ++c) {
                const int p = oct * 16 + c * 8 + pg;
                w[c] = W_out[(size_t)p * (DHID * DHID) + x * DHID + y];
            }
#pragma unroll
            for (int i = 0; i < 8; ++i) {
                const float av = COMP4(a4[i], xi);
#pragma unroll
                for (int c = 0; c < 2; ++c) acc[c][i] += av * w[c];
            }
        }
    }
#pragma unroll
    for (int c = 0; c < 2; ++c) {
        const int p = oct * 16 + c * 8 + pg;
#pragma unroll
        for (int i = 0; i < 8; ++i) {
            const float v = acc[c][i];
            const unsigned short hi = f2bf(v);
            const float lo = v - bf2f(hi);
            const size_t idx = (((size_t)(r0 + i)) * DPAIR + p) * DHID + y;
            Th[idx] = hi;
            Tl[idx] = f2bf(lo);
        }
    }
}

// Kernel C (REWRITTEN): out[b,i,j,p] = (sum_y bb[b,j,y]*T[b,i,p,y] + b_out[p])
//   * op_norm, via split-bf16 MFMA (Ah*Bh + Ah*Bl + Al*Bh; fp32 accumulate).
// One block per (b,i); 4 waves x 6 j-tiles x 8 p-tiles of 16x16, K=32 in ONE
// mfma_f32_16x16x32_bf16 per term. No LDS, no barriers. Both operands are
// 16B-contiguous per lane ([m][k] and [n][k] layouts); all reads L2-resident.
// Write-bound: 151 MB out.
__global__ __launch_bounds__(256) void k_main(
    const unsigned short* __restrict__ Th, const unsigned short* __restrict__ Tl,
    const unsigned short* __restrict__ bbh, const unsigned short* __restrict__ bbl,
    const float* __restrict__ b_out, const float* __restrict__ op_norm,
    float* __restrict__ out)
{
    const int t    = threadIdx.x;
    const int lane = t & 63;
    const int w    = t >> 6;           // wave 0..3
    const int lr   = lane & 15;        // m (j) / n (p) index within tile
    const int lg   = lane >> 4;        // k-group 0..3
    const int y0   = lg * 8;           // k base (8 consecutive y per lane)

    const int blk = blockIdx.x;        // b*NN + i
    const int b   = blk / NN;

    const unsigned short* tbh = Th + (size_t)blk * (DPAIR * DHID);
    const unsigned short* tbl = Tl + (size_t)blk * (DPAIR * DHID);
    const unsigned short* abh = bbh + (size_t)b * NN * DHID;
    const unsigned short* abl = bbl + (size_t)b * NN * DHID;

    // B-operand frags: B[y][p] = T[p][y]; lane holds T[pt*16+lr][y0..y0+7].
    bf16x8 fh[8], fl[8];
#pragma unroll
    for (int pt = 0; pt < 8; ++pt) {
        const size_t o = ((size_t)(pt * 16 + lr)) * DHID + y0;
        fh[pt] = *(const bf16x8*)(tbh + o);
        fl[pt] = *(const bf16x8*)(tbl + o);
    }

    float bo[8];
#pragma unroll
    for (int pt = 0; pt < 8; ++pt) bo[pt] = b_out[pt * 16 + lr];
    const float onorm = op_norm[0];

#pragma unroll 2
    for (int jj = 0; jj < 6; ++jj) {
        const int jt = w * 6 + jj;
        // A-operand frag: A[j][y]; lane holds bb[jt*16+lr][y0..y0+7].
        const size_t ao = ((size_t)(jt * 16 + lr)) * DHID + y0;
        const bf16x8 ah = *(const bf16x8*)(abh + ao);
        const bf16x8 al = *(const bf16x8*)(abl + ao);

        f32x4 acc[8];
#pragma unroll
        for (int pt = 0; pt < 8; ++pt) {
            f32x4 c = {0.f, 0.f, 0.f, 0.f};
            c = __builtin_amdgcn_mfma_f32_16x16x32_bf16(ah, fh[pt], c, 0, 0, 0);
            c = __builtin_amdgcn_mfma_f32_16x16x32_bf16(ah, fl[pt], c, 0, 0, 0);
            c = __builtin_amdgcn_mfma_f32_16x16x32_bf16(al, fh[pt], c, 0, 0, 0);
            acc[pt] = c;
        }

        // D layout: col(p)=lane&15, row(j_local)=lg*4+r  [m89-verified]
        float* orow = out + (((size_t)blk * NN) + jt * 16 + lg * 4) * DPAIR + lr;
#pragma unroll
        for (int r = 0; r < 4; ++r) {
#pragma unroll
            for (int pt = 0; pt < 8; ++pt)
                orow[(size_t)r * DPAIR + pt * 16] = (acc[pt][r] + bo[pt]) * onorm;
        }
    }
}

extern "C" void kernel_launch(void* const* d_in, const int* in_sizes, int n_in,
                              void* d_out, int out_size, void* d_ws, size_t ws_size,
                              hipStream_t stream)
{
    const float* m       = (const float*)d_in[0];
    const float* op_mask = (const float*)d_in[1];
    const float* op_norm = (const float*)d_in[2];
    const float* W_in    = (const float*)d_in[3];
    const float* b_in    = (const float*)d_in[4];
    const float* W_out   = (const float*)d_in[5];
    const float* b_out   = (const float*)d_in[6];
    float* out = (float*)d_out;

    float* ws = (float*)d_ws;
    float*          abuf = ws;                                   // 24576 f
    unsigned short* bbh  = (unsigned short*)(ws + 24576);        // 12288 f
    unsigned short* bbl  = (unsigned short*)(ws + 36864);        // 12288 f
    unsigned short* Th   = (unsigned short*)(ws + 49152);        // 1572864 f
    unsigned short* Tl   = (unsigned short*)(ws + 49152 + 1572864);

    hipLaunchKernelGGL(k_ab,   dim3(BSZ * NN),           dim3(256), 0, stream,
                       m, op_mask, W_in, b_in, abuf, bbh, bbl);
    hipLaunchKernelGGL(k_T,    dim3((BSZ * NN / 8) * 8), dim3(256), 0, stream,
                       abuf, W_out, Th, Tl);
    hipLaunchKernelGGL(k_main, dim3(BSZ * NN),           dim3(256), 0, stream,
                       Th, Tl, bbh, bbl, b_out, op_norm, out);
}